// Round 10
// baseline (410.133 us; speedup 1.0000x reference)
//
#include <hip/hip_runtime.h>
#include <hip/hip_bf16.h>

typedef unsigned short ushortT;
typedef __attribute__((ext_vector_type(8))) short v8s;
typedef __attribute__((ext_vector_type(4))) float v4f;

// Problem sizes (fixed by reference)
#define B_N   8192
#define S_N   512
#define F_N   64
#define R_N   4096
#define D_N   256
#define T_N   16
#define SF_N  (S_N * F_N)

#define ROWS  32            // rows per fused block
#define NBLK  (B_N / ROWS)  // 256 blocks = exactly 1/CU

__device__ __forceinline__ ushortT f2bf(float x) {
  __hip_bfloat16 b = __float2bfloat16(x);
  return *(ushortT*)&b;
}
__device__ __forceinline__ float bf2f(ushortT u) {
  __hip_bfloat16 b = *(__hip_bfloat16*)&u;
  return __bfloat162float(b);
}
__device__ __forceinline__ void splitHL8(const float* v, v8s& h8, v8s& l8) {
  union { short s[8]; v8s v; } H, L;
#pragma unroll
  for (int j = 0; j < 8; ++j) {
    const float x = v[j];
    const ushortT hb = f2bf(x);
    H.s[j] = (short)hb;
    L.s[j] = (short)f2bf(x - bf2f(hb));
  }
  h8 = H.v; l8 = L.v;
}

// ---- K0: reg -> frag-swizzled bf16 H/L + rsqh --------------------------------
// regHs[((g*8 + k0)*64 + lane)*8 + j] = reg[g*16 + (lane&15)][k0*32 + (lane>>4)*8 + j]
__global__ __launch_bounds__(256) void k_prep(const float* __restrict__ reg,
                                              ushortT* __restrict__ regHs,
                                              ushortT* __restrict__ regLs,
                                              float* __restrict__ rsqh) {
  const int g = blockIdx.x;   // 16-col group
  const int t = threadIdx.x;
  const int lane = t & 63;
  const int q = t >> 6;       // 0..3
  const int n16 = lane & 15;
  const int kg = lane >> 4;
  const int row = g * 16 + n16;
#pragma unroll
  for (int h = 0; h < 2; ++h) {
    const int k0 = q + h * 4;
    float v[8];
    *(float4*)&v[0] = *(const float4*)&reg[(size_t)row * D_N + k0 * 32 + kg * 8];
    *(float4*)&v[4] = *(const float4*)&reg[(size_t)row * D_N + k0 * 32 + kg * 8 + 4];
    v8s h8, l8;
    splitHL8(v, h8, l8);
    const size_t o = ((size_t)(g * 8 + k0) * 64 + lane) * 8;
    *(v8s*)&regHs[o] = h8;
    *(v8s*)&regLs[o] = l8;
  }
  const int r16 = t >> 4, seg = t & 15;
  const float* rp = &reg[(size_t)(g * 16 + r16) * D_N + seg * 16];
  float s = 0.f;
#pragma unroll
  for (int j = 0; j < 4; ++j) {
    const float4 v = *(const float4*)&rp[j * 4];
    s += v.x * v.x + v.y * v.y + v.z * v.z + v.w * v.w;
  }
#pragma unroll
  for (int m = 8; m >= 1; m >>= 1) s += __shfl_xor(s, m);
  if (seg == 0) rsqh[g * 16 + r16] = 0.5f * s;
}

// ---- Fused: mean(32 rows) -> proj -> H/L frag LDS -> MFMA score -> emit ----
__global__ __launch_bounds__(512, 2) void k_fused(const float* __restrict__ x,
                                                  const float* __restrict__ W,
                                                  const float* __restrict__ bias,
                                                  const float* __restrict__ reg,
                                                  const ushortT* __restrict__ regHs,
                                                  const ushortT* __restrict__ regLs,
                                                  const float* __restrict__ rsqh,
                                                  float* __restrict__ out,
                                                  float* __restrict__ lossPart) {
  __shared__ __align__(16) float xm[ROWS][68];       // mean (padded)   8.7 KB
  __shared__ __align__(16) ushortT xeHs[2][4096];    // xe H frags      16 KB
  __shared__ __align__(16) ushortT xeLs[2][4096];    // xe L frags      16 KB
  __shared__ float swv[8][ROWS];
  __shared__ int   swi[8][ROWS];
  __shared__ float srowloss[ROWS];
  __shared__ int   sbi[ROWS];

  const int t = threadIdx.x;
  const int w = t >> 6;       // wave 0..7
  const int lane = t & 63;
  const int bm0 = blockIdx.x * ROWS;

  // ---------- Phase 1a: temporal mean; wave w -> rows 4w..4w+3 ----------
  {
    const int row = 4 * w + (lane >> 4);
    const int f4 = (lane & 15) * 4;
    const float* xb = x + (size_t)(bm0 + row) * SF_N + f4;
    float4 a0 = make_float4(0.f, 0.f, 0.f, 0.f);
    float4 a1 = make_float4(0.f, 0.f, 0.f, 0.f);
    for (int s = 0; s < S_N; s += 8) {  // 8 x 1KB loads in flight
      const float* p = xb + (size_t)s * F_N;
      const float4 v0 = *(const float4*)&p[0 * F_N];
      const float4 v1 = *(const float4*)&p[1 * F_N];
      const float4 v2 = *(const float4*)&p[2 * F_N];
      const float4 v3 = *(const float4*)&p[3 * F_N];
      const float4 v4 = *(const float4*)&p[4 * F_N];
      const float4 v5 = *(const float4*)&p[5 * F_N];
      const float4 v6 = *(const float4*)&p[6 * F_N];
      const float4 v7 = *(const float4*)&p[7 * F_N];
      a0.x += v0.x + v2.x; a0.y += v0.y + v2.y; a0.z += v0.z + v2.z; a0.w += v0.w + v2.w;
      a1.x += v1.x + v3.x; a1.y += v1.y + v3.y; a1.z += v1.z + v3.z; a1.w += v1.w + v3.w;
      a0.x += v4.x + v6.x; a0.y += v4.y + v6.y; a0.z += v4.z + v6.z; a0.w += v4.w + v6.w;
      a1.x += v5.x + v7.x; a1.y += v5.y + v7.y; a1.z += v5.z + v7.z; a1.w += v5.w + v7.w;
    }
    const float inv = 1.0f / (float)S_N;
    xm[row][f4 + 0] = (a0.x + a1.x) * inv;
    xm[row][f4 + 1] = (a0.y + a1.y) * inv;
    xm[row][f4 + 2] = (a0.z + a1.z) * inv;
    xm[row][f4 + 3] = (a0.w + a1.w) * inv;
  }
  __syncthreads();

  // ---------- Phase 1b: projection -> H/L split -> frag-layout LDS ----------
  {
    const int prow = t >> 4;   // 0..31
    const int dgr = t & 15;    // d = dgr*16 .. +15
    const int n16 = prow & 15, rb = prow >> 4;
    float pv[16];
#pragma unroll
    for (int dd = 0; dd < 16; ++dd) {
      const int d = dgr * 16 + dd;
      float p = bias[d];
#pragma unroll
      for (int k4 = 0; k4 < 16; ++k4) {
        const float4 wv = *(const float4*)&W[(size_t)d * F_N + k4 * 4];
        const float4 xv = *(const float4*)&xm[prow][k4 * 4];
        p = fmaf(wv.x, xv.x, p); p = fmaf(wv.y, xv.y, p);
        p = fmaf(wv.z, xv.z, p); p = fmaf(wv.w, xv.w, p);
      }
      pv[dd] = p;
    }
#pragma unroll
    for (int o = 0; o < 2; ++o) {
      const int d0 = dgr * 16 + o * 8;
      const int k0 = d0 >> 5, kg = (d0 >> 3) & 3;
      v8s h8, l8;
      splitHL8(&pv[o * 8], h8, l8);
      const int idx = (k0 * 64 + kg * 16 + n16) * 8;
      *(v8s*)&xeHs[rb][idx] = h8;
      *(v8s*)&xeLs[rb][idx] = l8;
    }
  }
  __syncthreads();

  // ---------- Phase 2: MFMA score (3-pass H/L), cols w*512..w*512+511 ----------
  const int n16 = lane & 15;
  const int kg = lane >> 4;
  float bvj[2][4];
  int bij[2][4];
#pragma unroll
  for (int rb = 0; rb < 2; ++rb)
#pragma unroll
    for (int j = 0; j < 4; ++j) { bvj[rb][j] = 3.4e38f; bij[rb][j] = 0; }

  for (int c = 0; c < 8; ++c) {
    const int g0 = w * 32 + c * 4;  // 16-col group base
    v4f acc[2][4];
#pragma unroll
    for (int rb = 0; rb < 2; ++rb)
#pragma unroll
      for (int ni = 0; ni < 4; ++ni) acc[rb][ni] = (v4f){0.f, 0.f, 0.f, 0.f};
    const ushortT* BH = regHs + (size_t)g0 * 4096 + lane * 8;
    const ushortT* BL = regLs + (size_t)g0 * 4096 + lane * 8;
#pragma unroll
    for (int k0 = 0; k0 < 8; ++k0) {
      const int ao = (k0 * 64 + lane) * 8;
      const v8s ah0 = *(const v8s*)&xeHs[0][ao];
      const v8s al0 = *(const v8s*)&xeLs[0][ao];
      const v8s ah1 = *(const v8s*)&xeHs[1][ao];
      const v8s al1 = *(const v8s*)&xeLs[1][ao];
#pragma unroll
      for (int ni = 0; ni < 4; ++ni) {
        const v8s bh = *(const v8s*)&BH[(size_t)(ni * 8 + k0) * 512];
        const v8s bl = *(const v8s*)&BL[(size_t)(ni * 8 + k0) * 512];
        acc[0][ni] = __builtin_amdgcn_mfma_f32_16x16x32_bf16(ah0, bh, acc[0][ni], 0, 0, 0);
        acc[0][ni] = __builtin_amdgcn_mfma_f32_16x16x32_bf16(ah0, bl, acc[0][ni], 0, 0, 0);
        acc[0][ni] = __builtin_amdgcn_mfma_f32_16x16x32_bf16(al0, bh, acc[0][ni], 0, 0, 0);
        acc[1][ni] = __builtin_amdgcn_mfma_f32_16x16x32_bf16(ah1, bh, acc[1][ni], 0, 0, 0);
        acc[1][ni] = __builtin_amdgcn_mfma_f32_16x16x32_bf16(ah1, bl, acc[1][ni], 0, 0, 0);
        acc[1][ni] = __builtin_amdgcn_mfma_f32_16x16x32_bf16(al1, bh, acc[1][ni], 0, 0, 0);
      }
    }
#pragma unroll
    for (int ni = 0; ni < 4; ++ni) {   // ascending col groups -> lowest idx on ties
      const float rq = rsqh[(g0 + ni) * 16 + n16];
      const int col = (g0 + ni) * 16 + n16;
#pragma unroll
      for (int rb = 0; rb < 2; ++rb)
#pragma unroll
        for (int j = 0; j < 4; ++j) {  // row = rb*16 + kg*4 + j
          const float s = rq - acc[rb][ni][j];
          if (s < bvj[rb][j]) { bvj[rb][j] = s; bij[rb][j] = col; }
        }
    }
  }

  // reduce over the 16 n16-lanes (cols); rows (rb,kg,j) stay per-lane
#pragma unroll
  for (int rb = 0; rb < 2; ++rb)
#pragma unroll
    for (int j = 0; j < 4; ++j) {
      float v = bvj[rb][j];
      int ix = bij[rb][j];
#pragma unroll
      for (int m = 8; m >= 1; m >>= 1) {
        const float ov = __shfl_xor(v, m);
        const int oi = __shfl_xor(ix, m);
        if (ov < v || (ov == v && oi < ix)) { v = ov; ix = oi; }
      }
      if (n16 == 0) { swv[w][rb * 16 + kg * 4 + j] = v; swi[w][rb * 16 + kg * 4 + j] = ix; }
    }
  __syncthreads();

  // block-final argmin per row (waves = ascending col strips)
  if (t < ROWS) {
    float bv = swv[0][t];
    int bi = swi[0][t];
#pragma unroll
    for (int ww = 1; ww < 8; ++ww) {
      const float ov = swv[ww][t];
      const int oi = swi[ww][t];
      if (ov < bv || (ov == bv && oi < bi)) { bv = ov; bi = oi; }
    }
    sbi[t] = bi;
  }
  __syncthreads();

  // ---------- Phase 3: gather + emit 16 tokens/row + loss ----------
  {
    const int prow = t >> 4;   // 0..31
    const int seg = t & 15;    // d = seg*16 .. +15
    const int d16 = seg * 16;
    const int gr = bm0 + prow;
    const int ix = sbi[prow];
    const int n16p = prow & 15, rb = prow >> 4;
    __align__(16) float sel[16];  // registers: all indices compile-time below
    *(float4*)&sel[0]  = *(const float4*)&reg[(size_t)ix * D_N + d16];
    *(float4*)&sel[4]  = *(const float4*)&reg[(size_t)ix * D_N + d16 + 4];
    *(float4*)&sel[8]  = *(const float4*)&reg[(size_t)ix * D_N + d16 + 8];
    *(float4*)&sel[12] = *(const float4*)&reg[(size_t)ix * D_N + d16 + 12];
#pragma unroll
    for (int tt = 0; tt < T_N; ++tt) {
      float* op = &out[((size_t)gr * T_N + tt) * D_N + d16];
      *(float4*)&op[0]  = *(float4*)&sel[0];
      *(float4*)&op[4]  = *(float4*)&sel[4];
      *(float4*)&op[8]  = *(float4*)&sel[8];
      *(float4*)&op[12] = *(float4*)&sel[12];
    }
    float p = 0.f;
#pragma unroll
    for (int o = 0; o < 2; ++o) {
      const int d0 = d16 + o * 8;
      const int k0 = d0 >> 5, kgp = (d0 >> 3) & 3;
      const int idx = (k0 * 64 + kgp * 16 + n16p) * 8;
      const v8s vh = *(const v8s*)&xeHs[rb][idx];
      const v8s vl = *(const v8s*)&xeLs[rb][idx];
#pragma unroll
      for (int j = 0; j < 8; ++j) {
        const float xej = bf2f((ushortT)vh[j]) + bf2f((ushortT)vl[j]);
        const float dd = xej - sel[o * 8 + j];
        p = fmaf(dd, dd, p);
      }
    }
#pragma unroll
    for (int m = 8; m >= 1; m >>= 1) p += __shfl_xor(p, m);
    if (seg == 0) srowloss[prow] = p;
  }
  __syncthreads();
  if (t == 0) {
    float lp = 0.f;
#pragma unroll
    for (int r = 0; r < ROWS; ++r) lp += srowloss[r];
    lossPart[blockIdx.x] = lp;
  }
}

// ---- K2: loss = sum(parts)/B ----
__global__ __launch_bounds__(256) void k_loss(const float* __restrict__ lossPart,
                                              float* __restrict__ out) {
  __shared__ float ws4[4];
  const int t = threadIdx.x;
  float s = lossPart[t];  // exactly 256 parts
#pragma unroll
  for (int m = 32; m >= 1; m >>= 1) s += __shfl_xor(s, m);
  if ((t & 63) == 0) ws4[t >> 6] = s;
  __syncthreads();
  if (t == 0)
    out[(size_t)B_N * T_N * D_N] = (ws4[0] + ws4[1] + ws4[2] + ws4[3]) / (float)B_N;
}

extern "C" void kernel_launch(void* const* d_in, const int* in_sizes, int n_in,
                              void* d_out, int out_size, void* d_ws, size_t ws_size,
                              hipStream_t stream) {
  const float* x    = (const float*)d_in[0];
  const float* W    = (const float*)d_in[1];
  const float* bias = (const float*)d_in[2];
  const float* reg  = (const float*)d_in[3];
  float* out = (float*)d_out;

  // workspace: all regions fully rewritten every call (~4 MB)
  ushortT* regHs = (ushortT*)d_ws;                      // 2 MB, frag-swizzled
  ushortT* regLs = regHs + (size_t)R_N * D_N;           // 2 MB
  float*   rsqh  = (float*)(regLs + (size_t)R_N * D_N); // 4096
  float*   lossPart = rsqh + R_N;                       // 256

  k_prep<<<dim3(R_N / 16), dim3(256), 0, stream>>>(reg, regHs, regLs, rsqh);
  k_fused<<<dim3(NBLK), dim3(512), 0, stream>>>(x, W, bias, reg, regHs, regLs, rsqh,
                                                out, lossPart);
  k_loss<<<dim3(1), dim3(256), 0, stream>>>(lossPart, out);
}

// Round 11
// 388.727 us; speedup vs baseline: 1.0551x; 1.0551x over previous
//
#include <hip/hip_runtime.h>
#include <hip/hip_bf16.h>

typedef unsigned short ushortT;
typedef __attribute__((ext_vector_type(8))) short v8s;
typedef __attribute__((ext_vector_type(4))) float v4f;
typedef __attribute__((ext_vector_type(4))) float v4fx;

// Problem sizes (fixed by reference)
#define B_N   8192
#define S_N   512
#define F_N   64
#define R_N   4096
#define D_N   256
#define T_N   16
#define SF_N  (S_N * F_N)

#define ROWS  16            // rows per fused block
#define NBLK  (B_N / ROWS)  // 512 blocks; 2 resident/CU (LDS ~22 KB, VGPR<=128)

__device__ __forceinline__ ushortT f2bf(float x) {
  __hip_bfloat16 b = __float2bfloat16(x);
  return *(ushortT*)&b;
}
__device__ __forceinline__ float bf2f(ushortT u) {
  __hip_bfloat16 b = *(__hip_bfloat16*)&u;
  return __bfloat162float(b);
}
__device__ __forceinline__ void splitHL8(const float* v, v8s& h8, v8s& l8) {
  union { short s[8]; v8s v; } H, L;
#pragma unroll
  for (int j = 0; j < 8; ++j) {
    const float x = v[j];
    const ushortT hb = f2bf(x);
    H.s[j] = (short)hb;
    L.s[j] = (short)f2bf(x - bf2f(hb));
  }
  h8 = H.v; l8 = L.v;
}

// ---- K0: reg -> frag-swizzled bf16 H/L + rsqh --------------------------------
// regHs[((g*8 + k0)*64 + lane)*8 + j] = reg[g*16 + (lane&15)][k0*32 + (lane>>4)*8 + j]
__global__ __launch_bounds__(256) void k_prep(const float* __restrict__ reg,
                                              ushortT* __restrict__ regHs,
                                              ushortT* __restrict__ regLs,
                                              float* __restrict__ rsqh) {
  const int g = blockIdx.x;   // 16-col group
  const int t = threadIdx.x;
  const int lane = t & 63;
  const int q = t >> 6;       // 0..3
  const int n16 = lane & 15;
  const int kg = lane >> 4;
  const int row = g * 16 + n16;
#pragma unroll
  for (int h = 0; h < 2; ++h) {
    const int k0 = q + h * 4;
    float v[8];
    *(float4*)&v[0] = *(const float4*)&reg[(size_t)row * D_N + k0 * 32 + kg * 8];
    *(float4*)&v[4] = *(const float4*)&reg[(size_t)row * D_N + k0 * 32 + kg * 8 + 4];
    v8s h8, l8;
    splitHL8(v, h8, l8);
    const size_t o = ((size_t)(g * 8 + k0) * 64 + lane) * 8;
    *(v8s*)&regHs[o] = h8;
    *(v8s*)&regLs[o] = l8;
  }
  const int r16 = t >> 4, seg = t & 15;
  const float* rp = &reg[(size_t)(g * 16 + r16) * D_N + seg * 16];
  float s = 0.f;
#pragma unroll
  for (int j = 0; j < 4; ++j) {
    const float4 v = *(const float4*)&rp[j * 4];
    s += v.x * v.x + v.y * v.y + v.z * v.z + v.w * v.w;
  }
#pragma unroll
  for (int m = 8; m >= 1; m >>= 1) s += __shfl_xor(s, m);
  if (seg == 0) rsqh[g * 16 + r16] = 0.5f * s;
}

// ---- Fused: contiguous-stream mean -> proj -> frag LDS -> MFMA score -> emit ----
__global__ __launch_bounds__(512, 4) void k_fused(const float* __restrict__ x,
                                                  const float* __restrict__ W,
                                                  const float* __restrict__ bias,
                                                  const float* __restrict__ reg,
                                                  const ushortT* __restrict__ regHs,
                                                  const ushortT* __restrict__ regLs,
                                                  const float* __restrict__ rsqh,
                                                  float* __restrict__ out,
                                                  float* __restrict__ lossPart) {
  __shared__ __align__(16) float xm[ROWS][68];     // mean (padded)   4.4 KB
  __shared__ __align__(16) ushortT xeHs[4096];     // xe H frags      8 KB
  __shared__ __align__(16) ushortT xeLs[4096];     // xe L frags      8 KB
  __shared__ float swv[8][ROWS];
  __shared__ int   swi[8][ROWS];
  __shared__ float srowloss[ROWS];
  __shared__ int   sbi[ROWS];

  const int t = threadIdx.x;
  const int w = t >> 6;       // wave 0..7
  const int lane = t & 63;
  const int bm0 = blockIdx.x * ROWS;

  // ---------- Phase 1a: mean; wave w streams rows 2w,2w+1 as ONE contiguous 256 KB ----
  // Per instr: 64 lanes x 16 B = 1 KB fully contiguous. Non-temporal (no L2 pollution).
  {
    const v4fx* xw = (const v4fx*)(x + (size_t)(bm0 + 2 * w) * SF_N);
#pragma unroll
    for (int rr = 0; rr < 2; ++rr) {
      v4fx acc = (v4fx){0.f, 0.f, 0.f, 0.f};
#pragma unroll 1
      for (int gch = 0; gch < 16; ++gch) {      // 16 chunks x 8 instrs = 128 instrs/row
        const int i0 = rr * 128 + gch * 8;
#pragma unroll
        for (int u = 0; u < 8; ++u) {           // 8 x 1KB in flight
          const v4fx v = __builtin_nontemporal_load(&xw[(size_t)(i0 + u) * 64 + lane]);
          acc += v;
        }
      }
      // reduce over the 4 s-subgroups (lane>>4): xor 16, 32
      float c0 = acc[0], c1 = acc[1], c2 = acc[2], c3 = acc[3];
      c0 += __shfl_xor(c0, 16); c1 += __shfl_xor(c1, 16);
      c2 += __shfl_xor(c2, 16); c3 += __shfl_xor(c3, 16);
      c0 += __shfl_xor(c0, 32); c1 += __shfl_xor(c1, 32);
      c2 += __shfl_xor(c2, 32); c3 += __shfl_xor(c3, 32);
      if (lane < 16) {
        const float inv = 1.0f / (float)S_N;
        const int f4 = lane * 4;
        xm[2 * w + rr][f4 + 0] = c0 * inv;
        xm[2 * w + rr][f4 + 1] = c1 * inv;
        xm[2 * w + rr][f4 + 2] = c2 * inv;
        xm[2 * w + rr][f4 + 3] = c3 * inv;
      }
    }
  }
  __syncthreads();

  // ---------- Phase 1b: projection -> H/L split -> frag-layout LDS ----------
  {
    const int prow = t >> 5;   // 0..15
    const int dgr = t & 31;    // d = dgr*8 .. +7  (one v8s per thread)
    float pv[8];
#pragma unroll
    for (int dd = 0; dd < 8; ++dd) {
      const int d = dgr * 8 + dd;
      float p = bias[d];
#pragma unroll
      for (int k4 = 0; k4 < 16; ++k4) {
        const float4 wv = *(const float4*)&W[(size_t)d * F_N + k4 * 4];
        const float4 xv = *(const float4*)&xm[prow][k4 * 4];
        p = fmaf(wv.x, xv.x, p); p = fmaf(wv.y, xv.y, p);
        p = fmaf(wv.z, xv.z, p); p = fmaf(wv.w, xv.w, p);
      }
      pv[dd] = p;
    }
    const int d0 = dgr * 8;
    const int k0 = d0 >> 5, kg = (d0 >> 3) & 3;
    v8s h8, l8;
    splitHL8(pv, h8, l8);
    const int idx = (k0 * 64 + kg * 16 + prow) * 8;
    *(v8s*)&xeHs[idx] = h8;
    *(v8s*)&xeLs[idx] = l8;
  }
  __syncthreads();

  // ---------- Phase 2: MFMA score (3-pass H/L), cols w*512..w*512+511 ----------
  const int n16 = lane & 15;
  const int kg = lane >> 4;
  float bvj[4];
  int bij[4];
#pragma unroll
  for (int j = 0; j < 4; ++j) { bvj[j] = 3.4e38f; bij[j] = 0; }

  for (int c = 0; c < 8; ++c) {
    const int g0 = w * 32 + c * 4;  // 16-col group base
    v4f acc[4];
#pragma unroll
    for (int ni = 0; ni < 4; ++ni) acc[ni] = (v4f){0.f, 0.f, 0.f, 0.f};
    const ushortT* BH = regHs + (size_t)g0 * 4096 + lane * 8;
    const ushortT* BL = regLs + (size_t)g0 * 4096 + lane * 8;
#pragma unroll
    for (int k0 = 0; k0 < 8; ++k0) {
      const int ao = (k0 * 64 + lane) * 8;
      const v8s ah = *(const v8s*)&xeHs[ao];
      const v8s al = *(const v8s*)&xeLs[ao];
#pragma unroll
      for (int ni = 0; ni < 4; ++ni) {
        const v8s bh = *(const v8s*)&BH[(size_t)(ni * 8 + k0) * 512];
        const v8s bl = *(const v8s*)&BL[(size_t)(ni * 8 + k0) * 512];
        acc[ni] = __builtin_amdgcn_mfma_f32_16x16x32_bf16(ah, bh, acc[ni], 0, 0, 0);
        acc[ni] = __builtin_amdgcn_mfma_f32_16x16x32_bf16(ah, bl, acc[ni], 0, 0, 0);
        acc[ni] = __builtin_amdgcn_mfma_f32_16x16x32_bf16(al, bh, acc[ni], 0, 0, 0);
      }
    }
#pragma unroll
    for (int ni = 0; ni < 4; ++ni) {   // ascending col groups -> lowest idx on ties
      const float rq = rsqh[(g0 + ni) * 16 + n16];
      const int col = (g0 + ni) * 16 + n16;
#pragma unroll
      for (int j = 0; j < 4; ++j) {    // row = kg*4 + j
        const float s = rq - acc[ni][j];
        if (s < bvj[j]) { bvj[j] = s; bij[j] = col; }
      }
    }
  }

  // reduce over the 16 n16-lanes (cols); rows (kg,j) stay per-lane
#pragma unroll
  for (int j = 0; j < 4; ++j) {
    float v = bvj[j];
    int ix = bij[j];
#pragma unroll
    for (int m = 8; m >= 1; m >>= 1) {
      const float ov = __shfl_xor(v, m);
      const int oi = __shfl_xor(ix, m);
      if (ov < v || (ov == v && oi < ix)) { v = ov; ix = oi; }
    }
    if (n16 == 0) { swv[w][kg * 4 + j] = v; swi[w][kg * 4 + j] = ix; }
  }
  __syncthreads();

  // block-final argmin per row (waves = ascending col strips)
  if (t < ROWS) {
    float bv = swv[0][t];
    int bi = swi[0][t];
#pragma unroll
    for (int ww = 1; ww < 8; ++ww) {
      const float ov = swv[ww][t];
      const int oi = swi[ww][t];
      if (ov < bv || (ov == bv && oi < bi)) { bv = ov; bi = oi; }
    }
    sbi[t] = bi;
  }
  __syncthreads();

  // ---------- Phase 3: gather + emit 16 tokens/row + loss ----------
  {
    const int prow = t >> 5;   // 0..15
    const int seg = t & 31;    // d = seg*8 .. +7
    const int d8 = seg * 8;
    const int gr = bm0 + prow;
    const int ix = sbi[prow];
    __align__(16) float sel[8];  // registers: static indices only
    *(float4*)&sel[0] = *(const float4*)&reg[(size_t)ix * D_N + d8];
    *(float4*)&sel[4] = *(const float4*)&reg[(size_t)ix * D_N + d8 + 4];
#pragma unroll
    for (int tt = 0; tt < T_N; ++tt) {
      float* op = &out[((size_t)gr * T_N + tt) * D_N + d8];
      *(float4*)&op[0] = *(float4*)&sel[0];
      *(float4*)&op[4] = *(float4*)&sel[4];
    }
    // loss: reconstruct xe = H + L from frag LDS
    const int k0 = d8 >> 5, kgp = (d8 >> 3) & 3;
    const int idx = (k0 * 64 + kgp * 16 + prow) * 8;
    const v8s vh = *(const v8s*)&xeHs[idx];
    const v8s vl = *(const v8s*)&xeLs[idx];
    float p = 0.f;
#pragma unroll
    for (int j = 0; j < 8; ++j) {
      const float xej = bf2f((ushortT)vh[j]) + bf2f((ushortT)vl[j]);
      const float dd = xej - sel[j];
      p = fmaf(dd, dd, p);
    }
#pragma unroll
    for (int m = 16; m >= 1; m >>= 1) p += __shfl_xor(p, m);  // sum over 32 seg-lanes
    if (seg == 0) srowloss[prow] = p;
  }
  __syncthreads();
  if (t == 0) {
    float lp = 0.f;
#pragma unroll
    for (int r = 0; r < ROWS; ++r) lp += srowloss[r];
    lossPart[blockIdx.x] = lp;
  }
}

// ---- K2: loss = sum(parts)/B ----
__global__ __launch_bounds__(512) void k_loss(const float* __restrict__ lossPart,
                                              float* __restrict__ out) {
  __shared__ float ws8[8];
  const int t = threadIdx.x;
  float s = lossPart[t];  // exactly 512 parts
#pragma unroll
  for (int m = 32; m >= 1; m >>= 1) s += __shfl_xor(s, m);
  if ((t & 63) == 0) ws8[t >> 6] = s;
  __syncthreads();
  if (t == 0) {
    float a = 0.f;
#pragma unroll
    for (int i = 0; i < 8; ++i) a += ws8[i];
    out[(size_t)B_N * T_N * D_N] = a / (float)B_N;
  }
}

extern "C" void kernel_launch(void* const* d_in, const int* in_sizes, int n_in,
                              void* d_out, int out_size, void* d_ws, size_t ws_size,
                              hipStream_t stream) {
  const float* x    = (const float*)d_in[0];
  const float* W    = (const float*)d_in[1];
  const float* bias = (const float*)d_in[2];
  const float* reg  = (const float*)d_in[3];
  float* out = (float*)d_out;

  // workspace: all regions fully rewritten every call (~4 MB)
  ushortT* regHs = (ushortT*)d_ws;                      // 2 MB, frag-swizzled
  ushortT* regLs = regHs + (size_t)R_N * D_N;           // 2 MB
  float*   rsqh  = (float*)(regLs + (size_t)R_N * D_N); // 4096
  float*   lossPart = rsqh + R_N;                       // 512

  k_prep<<<dim3(R_N / 16), dim3(256), 0, stream>>>(reg, regHs, regLs, rsqh);
  k_fused<<<dim3(NBLK), dim3(512), 0, stream>>>(x, W, bias, reg, regHs, regLs, rsqh,
                                                out, lossPart);
  k_loss<<<dim3(1), dim3(512), 0, stream>>>(lossPart, out);
}